// Round 5
// baseline (446.057 us; speedup 1.0000x reference)
//
#include <hip/hip_runtime.h>

#define N_NODES 50000
#define N_EDGES 1600000
#define ET (N_EDGES + N_NODES)   // edges + self-loops
#define DF 128                   // feature / hidden dim
#define SLOPE 0.2f

#define NB 196        // coarse buckets: dst >> 8 (50000/256)
#define BCAP 10240    // slots per bucket (avg 8448, sigma ~92 -> +19 sigma)
#define P1_CHUNK 4096 // edges per bin_pass block (16 per thread)

// ---------------------------------------------------------------------------
// Dual GEMM: out = X @ W.  X: [M,128], W: [128,128].
// 128x128 block tile, 256 threads, 8x8 micro-tile, BK=32.
// blockIdx.y: 0 -> Wl/outL, 1 -> Wr/outR.
// ---------------------------------------------------------------------------
__global__ __launch_bounds__(256) void gemm_dual(
    const float* __restrict__ X,
    const float* __restrict__ Wl, const float* __restrict__ Wr,
    float* __restrict__ outL, float* __restrict__ outR, int M)
{
    const int which = blockIdx.y;
    const float* W = which ? Wr : Wl;
    float* out = which ? outR : outL;

    __shared__ float xs[32][132];   // x tile transposed: xs[k][row]
    __shared__ float wsh[32][132];  // w tile: wsh[k][col]

    const int t  = threadIdx.x;
    const int tx = t & 15, ty = t >> 4;
    const int row0 = blockIdx.x * 128;

    float acc[8][8];
#pragma unroll
    for (int i = 0; i < 8; i++)
#pragma unroll
        for (int j = 0; j < 8; j++) acc[i][j] = 0.f;

    // staging indices
    const int sr = t >> 1;          // 0..127 : row for X load (2 threads/row)
    const int sk = (t & 1) * 16;    // k half base for X load
    const int wk = t >> 3;          // 0..31  : k row for W load (8 threads/row)
    const int wc = (t & 7) * 16;    // col base for W load (16 cols)

    for (int kb = 0; kb < 128; kb += 32) {
        int xrw = row0 + sr; if (xrw >= M) xrw = M - 1;   // clamp; store guarded
        const float* xp = X + (size_t)xrw * DF + kb + sk;
        float4 x0 = *(const float4*)(xp + 0);
        float4 x1 = *(const float4*)(xp + 4);
        float4 x2 = *(const float4*)(xp + 8);
        float4 x3 = *(const float4*)(xp + 12);
        xs[sk + 0][sr] = x0.x;  xs[sk + 1][sr] = x0.y;
        xs[sk + 2][sr] = x0.z;  xs[sk + 3][sr] = x0.w;
        xs[sk + 4][sr] = x1.x;  xs[sk + 5][sr] = x1.y;
        xs[sk + 6][sr] = x1.z;  xs[sk + 7][sr] = x1.w;
        xs[sk + 8][sr] = x2.x;  xs[sk + 9][sr] = x2.y;
        xs[sk + 10][sr] = x2.z; xs[sk + 11][sr] = x2.w;
        xs[sk + 12][sr] = x3.x; xs[sk + 13][sr] = x3.y;
        xs[sk + 14][sr] = x3.z; xs[sk + 15][sr] = x3.w;

        const float* wp = W + (size_t)(kb + wk) * DF + wc;
        *(float4*)(&wsh[wk][wc + 0])  = *(const float4*)(wp + 0);
        *(float4*)(&wsh[wk][wc + 4])  = *(const float4*)(wp + 4);
        *(float4*)(&wsh[wk][wc + 8])  = *(const float4*)(wp + 8);
        *(float4*)(&wsh[wk][wc + 12]) = *(const float4*)(wp + 12);
        __syncthreads();
#pragma unroll
        for (int kk = 0; kk < 32; kk++) {
            float4 a0 = *(const float4*)(&xs[kk][ty * 8]);
            float4 a1 = *(const float4*)(&xs[kk][ty * 8 + 4]);
            float4 b0 = *(const float4*)(&wsh[kk][tx * 8]);
            float4 b1 = *(const float4*)(&wsh[kk][tx * 8 + 4]);
            float av[8] = {a0.x, a0.y, a0.z, a0.w, a1.x, a1.y, a1.z, a1.w};
            float bv[8] = {b0.x, b0.y, b0.z, b0.w, b1.x, b1.y, b1.z, b1.w};
#pragma unroll
            for (int i = 0; i < 8; i++)
#pragma unroll
                for (int j = 0; j < 8; j++)
                    acc[i][j] += av[i] * bv[j];
        }
        __syncthreads();
    }
#pragma unroll
    for (int i = 0; i < 8; i++) {
        int r = row0 + ty * 8 + i;
        if (r < M) {
            float* op = out + (size_t)r * DF + tx * 8;
            *(float4*)(op)     = make_float4(acc[i][0], acc[i][1], acc[i][2], acc[i][3]);
            *(float4*)(op + 4) = make_float4(acc[i][4], acc[i][5], acc[i][6], acc[i][7]);
        }
    }
}

// ---------------------------------------------------------------------------
// CSR build, two-level bucket sort.
// Pass 1: bin edges by coarse bucket (dst>>8). Packed 4B: src | (dst&255)<<16.
// (src < 50000 fits in 16 bits.)
// ---------------------------------------------------------------------------
__global__ __launch_bounds__(256) void bin_pass(const int* __restrict__ ei,
                                                int* __restrict__ g_count,
                                                int* __restrict__ bucket_mem)
{
    __shared__ int cnt[NB], base[NB], cnt2[NB];
    const int tid = threadIdx.x;
    for (int i = tid; i < NB; i += 256) { cnt[i] = 0; cnt2[i] = 0; }
    __syncthreads();

    const int e0 = blockIdx.x * P1_CHUNK;
    int srcv[16], dstv[16];
#pragma unroll
    for (int i = 0; i < 16; i++) {
        int eid = e0 + i * 256 + tid;   // coalesced
        int s = 0, d = -1;
        if (eid < ET) {
            if (eid < N_EDGES) { s = ei[eid]; d = ei[N_EDGES + eid]; }
            else               { s = d = eid - N_EDGES; }
        }
        srcv[i] = s; dstv[i] = d;
        if (d >= 0) atomicAdd(&cnt[d >> 8], 1);
    }
    __syncthreads();
    for (int i = tid; i < NB; i += 256)
        base[i] = (cnt[i] > 0) ? atomicAdd(&g_count[i], cnt[i]) : 0;
    __syncthreads();
#pragma unroll
    for (int i = 0; i < 16; i++) {
        int d = dstv[i];
        if (d >= 0) {
            int b = d >> 8;
            int r = atomicAdd(&cnt2[b], 1);
            int slot = base[b] + r;
            if (slot < BCAP)
                bucket_mem[(size_t)b * BCAP + slot] =
                    (srcv[i] & 0xFFFF) | ((d & 255) << 16);
        }
    }
}

// Exclusive scan over the NB bucket counts (single tiny block).
__global__ __launch_bounds__(256) void bucket_scan(const int* __restrict__ g_count,
                                                   int* __restrict__ bucket_base)
{
    __shared__ int v[256];
    int tid = threadIdx.x;
    int c = (tid < NB) ? g_count[tid] : 0;
    v[tid] = c; __syncthreads();
    for (int d = 1; d < 256; d <<= 1) {
        int x = (tid >= d) ? v[tid - d] : 0;
        __syncthreads();
        v[tid] += x;
        __syncthreads();
    }
    if (tid < NB) bucket_base[tid] = v[tid] - c;
}

// Pass 2: one block per bucket. LDS-stage edges, local 256-node hist + scan
// (produces row_ptr directly), then scatter csr_src into the bucket's
// contiguous region (block-private -> full-line L2 writebacks).
__global__ __launch_bounds__(256) void csr_pass(const int* __restrict__ g_count,
                                                const int* __restrict__ bucket_base,
                                                const int* __restrict__ bucket_mem,
                                                int* __restrict__ row_ptr,
                                                int* __restrict__ csr_src)
{
    __shared__ int sh_edges[BCAP];
    __shared__ int hist[256], offs[256], excl[256], cnt2[256];
    const int b = blockIdx.x, tid = threadIdx.x;
    int m = g_count[b]; if (m > BCAP) m = BCAP;
    hist[tid] = 0; cnt2[tid] = 0;
    __syncthreads();
    const int* bm = bucket_mem + (size_t)b * BCAP;
    for (int i = tid; i < m; i += 256) {
        int p = bm[i];
        sh_edges[i] = p;
        atomicAdd(&hist[(p >> 16) & 255], 1);
    }
    __syncthreads();
    offs[tid] = hist[tid]; __syncthreads();
    for (int d = 1; d < 256; d <<= 1) {
        int x = (tid >= d) ? offs[tid - d] : 0;
        __syncthreads();
        offs[tid] += x;
        __syncthreads();
    }
    excl[tid] = offs[tid] - hist[tid];
    const int node0 = b << 8;
    const int base_csr = bucket_base[b];
    if (node0 + tid < N_NODES) row_ptr[node0 + tid] = base_csr + excl[tid];
    if (b == 0 && tid == 0) row_ptr[N_NODES] = ET;
    __syncthreads();
    for (int i = tid; i < m; i += 256) {
        int p = sh_edges[i];
        int dl = (p >> 16) & 255;
        int r = atomicAdd(&cnt2[dl], 1);
        csr_src[base_csr + excl[dl] + r] = p & 0xFFFF;
    }
}

// ---------------------------------------------------------------------------
// Fused scores + softmax + aggregate: one wave per dst node, 4 edges/iter.
// Quarter-wave (16 lanes) per edge; lane covers 8 channels (2x float4);
// head = ql/4. Two independent dwordx4 gathers per iteration for MLP.
// ---------------------------------------------------------------------------
__global__ __launch_bounds__(256) void fused_agg(
    const float* __restrict__ xl, const float* __restrict__ xr,
    const int* __restrict__ row_ptr, const int* __restrict__ csr_src,
    const float* __restrict__ att, const float* __restrict__ bias,
    float* __restrict__ out)
{
    int t = threadIdx.x;
    int wave = t >> 6, l = t & 63;
    int q = l >> 4, ql = l & 15;            // quarter-wave id, lane within
    int n = blockIdx.x * 4 + wave;
    if (n >= N_NODES) return;
    int beg = row_ptr[n], end = row_ptr[n + 1];

    const int c0 = 8 * ql;
    const float* xrp = xr + (size_t)n * DF + c0;
    float4 xr0 = *(const float4*)(xrp);
    float4 xr1 = *(const float4*)(xrp + 4);
    float4 at0 = *(const float4*)(att + c0);
    float4 at1 = *(const float4*)(att + c0 + 4);

    float a0 = 0.f, a1 = 0.f, a2 = 0.f, a3 = 0.f;
    float a4 = 0.f, a5 = 0.f, a6 = 0.f, a7 = 0.f, den = 0.f;

    for (int base = beg; base < end; base += 64) {
        int cnt = end - base; if (cnt > 64) cnt = 64;
        int my_src = 0;
        if (base + l < end) my_src = csr_src[base + l];   // coalesced batch load
        int nq = (cnt + 3) >> 2;
        for (int j = 0; j < nq; j++) {
            int eidx = 4 * j + q;                         // edge slot for my quarter
            int s = __shfl(my_src, eidx);
            const float* row = xl + (size_t)s * DF + c0;
            float4 v0 = *(const float4*)(row);
            float4 v1 = *(const float4*)(row + 4);
            float m0 = v0.x + xr0.x, m1 = v0.y + xr0.y;
            float m2 = v0.z + xr0.z, m3 = v0.w + xr0.w;
            float m4 = v1.x + xr1.x, m5 = v1.y + xr1.y;
            float m6 = v1.z + xr1.z, m7 = v1.w + xr1.w;
            m0 = m0 > 0.f ? m0 : SLOPE * m0;
            m1 = m1 > 0.f ? m1 : SLOPE * m1;
            m2 = m2 > 0.f ? m2 : SLOPE * m2;
            m3 = m3 > 0.f ? m3 : SLOPE * m3;
            m4 = m4 > 0.f ? m4 : SLOPE * m4;
            m5 = m5 > 0.f ? m5 : SLOPE * m5;
            m6 = m6 > 0.f ? m6 : SLOPE * m6;
            m7 = m7 > 0.f ? m7 : SLOPE * m7;
            float p = m0 * at0.x + m1 * at0.y + m2 * at0.z + m3 * at0.w
                    + m4 * at1.x + m5 * at1.y + m6 * at1.z + m7 * at1.w;
            // reduce over the 4 lanes of this head group (within quarter)
            p += __shfl_xor(p, 1);
            p += __shfl_xor(p, 2);
            float e = (eidx < cnt) ? __expf(p) : 0.f;
            a0 += e * v0.x; a1 += e * v0.y; a2 += e * v0.z; a3 += e * v0.w;
            a4 += e * v1.x; a5 += e * v1.y; a6 += e * v1.z; a7 += e * v1.w;
            den += e;
        }
    }

    // combine the four quarter-wave accumulators (same channels, diff edges)
#define CMB(x) x += __shfl_xor(x, 16); x += __shfl_xor(x, 32);
    CMB(a0) CMB(a1) CMB(a2) CMB(a3) CMB(a4) CMB(a5) CMB(a6) CMB(a7) CMB(den)
#undef CMB

    if (q == 0) {
        float inv = 1.f / (den + 1e-16f);
        float4 b0 = *(const float4*)(bias + c0);
        float4 b1 = *(const float4*)(bias + c0 + 4);
        float4 o0, o1;
        o0.x = fmaxf(a0 * inv + b0.x, 0.f);
        o0.y = fmaxf(a1 * inv + b0.y, 0.f);
        o0.z = fmaxf(a2 * inv + b0.z, 0.f);
        o0.w = fmaxf(a3 * inv + b0.w, 0.f);
        o1.x = fmaxf(a4 * inv + b1.x, 0.f);
        o1.y = fmaxf(a5 * inv + b1.y, 0.f);
        o1.z = fmaxf(a6 * inv + b1.z, 0.f);
        o1.w = fmaxf(a7 * inv + b1.w, 0.f);
        float* op = out + (size_t)n * DF + c0;
        *(float4*)(op)     = o0;
        *(float4*)(op + 4) = o1;
    }
}

// ---------------------------------------------------------------------------
extern "C" void kernel_launch(void* const* d_in, const int* in_sizes, int n_in,
                              void* d_out, int out_size, void* d_ws, size_t ws_size,
                              hipStream_t stream)
{
    (void)in_sizes; (void)n_in; (void)out_size; (void)ws_size;

    const float* x    = (const float*)d_in[0];
    const int*   ei   = (const int*)d_in[1];
    const float* W1l  = (const float*)d_in[2];
    const float* W1r  = (const float*)d_in[3];
    const float* att1 = (const float*)d_in[4];
    const float* b1   = (const float*)d_in[5];
    const float* W2l  = (const float*)d_in[6];
    const float* W2r  = (const float*)d_in[7];
    const float* att2 = (const float*)d_in[8];
    const float* b2   = (const float*)d_in[9];
    float* out = (float*)d_out;

    char* ws = (char*)d_ws;
    size_t off = 0;
    const size_t NF = (size_t)N_NODES * DF * sizeof(float);   // 25.6 MB
    float* A  = (float*)(ws + off); off += NF;                // xl
    float* B  = (float*)(ws + off); off += NF;                // xr
    float* C  = (float*)(ws + off); off += NF;                // layer-1 output h
    int* bucket_mem  = (int*)(ws + off); off += (size_t)NB * BCAP * sizeof(int);
    int* g_count     = (int*)(ws + off); off += 256 * sizeof(int);
    int* bucket_base = (int*)(ws + off); off += 256 * sizeof(int);
    int* row_ptr     = (int*)(ws + off); off += (size_t)(N_NODES + 1) * sizeof(int);
    int* csr_src     = (int*)(ws + off); off += (size_t)ET * sizeof(int);

    // ---- CSR over dst (shared by both layers) ----
    hipMemsetAsync(g_count, 0, NB * sizeof(int), stream);
    bin_pass<<<(ET + P1_CHUNK - 1) / P1_CHUNK, 256, 0, stream>>>(ei, g_count, bucket_mem);
    bucket_scan<<<1, 256, 0, stream>>>(g_count, bucket_base);
    csr_pass<<<NB, 256, 0, stream>>>(g_count, bucket_base, bucket_mem, row_ptr, csr_src);

    dim3 gg((N_NODES + 127) / 128, 2);

    // ---- layer 1 ----
    gemm_dual<<<gg, 256, 0, stream>>>(x, W1l, W1r, A, B, N_NODES);
    fused_agg<<<(N_NODES + 3) / 4, 256, 0, stream>>>(A, B, row_ptr, csr_src, att1, b1, C);

    // ---- layer 2 ----
    gemm_dual<<<gg, 256, 0, stream>>>(C, W2l, W2r, A, B, N_NODES);
    fused_agg<<<(N_NODES + 3) / 4, 256, 0, stream>>>(A, B, row_ptr, csr_src, att2, b2, out);
}

// Round 6
// 441.870 us; speedup vs baseline: 1.0095x; 1.0095x over previous
//
#include <hip/hip_runtime.h>

#define N_NODES 50000
#define N_EDGES 1600000
#define ET (N_EDGES + N_NODES)   // edges + self-loops
#define DF 128                   // feature / hidden dim
#define SLOPE 0.2f

#define NB 196        // coarse buckets: dst >> 8 (50000/256)
#define BCAP 10240    // slots per bucket (avg 8448, sigma ~92 -> +19 sigma)
#define P1_CHUNK 4096 // edges per bin_pass block (16 per thread)

// ---------------------------------------------------------------------------
// Dual GEMM: out = X @ W.  X: [M,128], W: [128,128].
// 128x128 block tile, 256 threads, 8x8 micro-tile, BK=32.
// blockIdx.y: 0 -> Wl/outL, 1 -> Wr/outR.  782 blocks = 3.05/CU.
// ---------------------------------------------------------------------------
__global__ __launch_bounds__(256) void gemm_dual(
    const float* __restrict__ X,
    const float* __restrict__ Wl, const float* __restrict__ Wr,
    float* __restrict__ outL, float* __restrict__ outR, int M)
{
    const int which = blockIdx.y;
    const float* W = which ? Wr : Wl;
    float* out = which ? outR : outL;

    __shared__ float xs[32][132];   // x tile transposed: xs[k][row]
    __shared__ float wsh[32][132];  // w tile: wsh[k][col]

    const int t  = threadIdx.x;
    const int tx = t & 15, ty = t >> 4;
    const int row0 = blockIdx.x * 128;

    float acc[8][8];
#pragma unroll
    for (int i = 0; i < 8; i++)
#pragma unroll
        for (int j = 0; j < 8; j++) acc[i][j] = 0.f;

    const int sr = t >> 1;          // 0..127 : row for X load (2 threads/row)
    const int sk = (t & 1) * 16;    // k half base for X load
    const int wk = t >> 3;          // 0..31  : k row for W load (8 threads/row)
    const int wc = (t & 7) * 16;    // col base for W load (16 cols)

    for (int kb = 0; kb < 128; kb += 32) {
        int xrw = row0 + sr; if (xrw >= M) xrw = M - 1;   // clamp; store guarded
        const float* xp = X + (size_t)xrw * DF + kb + sk;
        float4 x0 = *(const float4*)(xp + 0);
        float4 x1 = *(const float4*)(xp + 4);
        float4 x2 = *(const float4*)(xp + 8);
        float4 x3 = *(const float4*)(xp + 12);
        xs[sk + 0][sr] = x0.x;  xs[sk + 1][sr] = x0.y;
        xs[sk + 2][sr] = x0.z;  xs[sk + 3][sr] = x0.w;
        xs[sk + 4][sr] = x1.x;  xs[sk + 5][sr] = x1.y;
        xs[sk + 6][sr] = x1.z;  xs[sk + 7][sr] = x1.w;
        xs[sk + 8][sr] = x2.x;  xs[sk + 9][sr] = x2.y;
        xs[sk + 10][sr] = x2.z; xs[sk + 11][sr] = x2.w;
        xs[sk + 12][sr] = x3.x; xs[sk + 13][sr] = x3.y;
        xs[sk + 14][sr] = x3.z; xs[sk + 15][sr] = x3.w;

        const float* wp = W + (size_t)(kb + wk) * DF + wc;
        *(float4*)(&wsh[wk][wc + 0])  = *(const float4*)(wp + 0);
        *(float4*)(&wsh[wk][wc + 4])  = *(const float4*)(wp + 4);
        *(float4*)(&wsh[wk][wc + 8])  = *(const float4*)(wp + 8);
        *(float4*)(&wsh[wk][wc + 12]) = *(const float4*)(wp + 12);
        __syncthreads();
#pragma unroll
        for (int kk = 0; kk < 32; kk++) {
            float4 a0 = *(const float4*)(&xs[kk][ty * 8]);
            float4 a1 = *(const float4*)(&xs[kk][ty * 8 + 4]);
            float4 b0 = *(const float4*)(&wsh[kk][tx * 8]);
            float4 b1 = *(const float4*)(&wsh[kk][tx * 8 + 4]);
            float av[8] = {a0.x, a0.y, a0.z, a0.w, a1.x, a1.y, a1.z, a1.w};
            float bv[8] = {b0.x, b0.y, b0.z, b0.w, b1.x, b1.y, b1.z, b1.w};
#pragma unroll
            for (int i = 0; i < 8; i++)
#pragma unroll
                for (int j = 0; j < 8; j++)
                    acc[i][j] += av[i] * bv[j];
        }
        __syncthreads();
    }
#pragma unroll
    for (int i = 0; i < 8; i++) {
        int r = row0 + ty * 8 + i;
        if (r < M) {
            float* op = out + (size_t)r * DF + tx * 8;
            *(float4*)(op)     = make_float4(acc[i][0], acc[i][1], acc[i][2], acc[i][3]);
            *(float4*)(op + 4) = make_float4(acc[i][4], acc[i][5], acc[i][6], acc[i][7]);
        }
    }
}

// ---------------------------------------------------------------------------
// CSR build, two-level bucket sort.
// Pass 1: bin edges by coarse bucket (dst>>8). Packed 4B: src | (dst&255)<<16.
// ---------------------------------------------------------------------------
__global__ __launch_bounds__(256) void bin_pass(const int* __restrict__ ei,
                                                int* __restrict__ g_count,
                                                int* __restrict__ bucket_mem)
{
    __shared__ int cnt[NB], base[NB], cnt2[NB];
    const int tid = threadIdx.x;
    for (int i = tid; i < NB; i += 256) { cnt[i] = 0; cnt2[i] = 0; }
    __syncthreads();

    const int e0 = blockIdx.x * P1_CHUNK;
    int srcv[16], dstv[16];
#pragma unroll
    for (int i = 0; i < 16; i++) {
        int eid = e0 + i * 256 + tid;   // coalesced
        int s = 0, d = -1;
        if (eid < ET) {
            if (eid < N_EDGES) { s = ei[eid]; d = ei[N_EDGES + eid]; }
            else               { s = d = eid - N_EDGES; }
        }
        srcv[i] = s; dstv[i] = d;
        if (d >= 0) atomicAdd(&cnt[d >> 8], 1);
    }
    __syncthreads();
    for (int i = tid; i < NB; i += 256)
        base[i] = (cnt[i] > 0) ? atomicAdd(&g_count[i], cnt[i]) : 0;
    __syncthreads();
#pragma unroll
    for (int i = 0; i < 16; i++) {
        int d = dstv[i];
        if (d >= 0) {
            int b = d >> 8;
            int r = atomicAdd(&cnt2[b], 1);
            int slot = base[b] + r;
            if (slot < BCAP)
                bucket_mem[(size_t)b * BCAP + slot] =
                    (srcv[i] & 0xFFFF) | ((d & 255) << 16);
        }
    }
}

// Pass 2: one block per bucket. Inline scan of the NB bucket counts (folds the
// old bucket_scan dispatch), LDS-stage edges, local 256-node hist + scan
// (produces row_ptr directly), then scatter csr_src (ushort) into the bucket's
// contiguous region (block-private -> full-line L2 writebacks).
__global__ __launch_bounds__(256) void csr_pass(const int* __restrict__ g_count,
                                                const int* __restrict__ bucket_mem,
                                                int* __restrict__ row_ptr,
                                                unsigned short* __restrict__ csr_src)
{
    __shared__ int sh_edges[BCAP];
    __shared__ int hist[256], offs[256], excl[256], cnt2[256];
    __shared__ int gsc[256];
    const int b = blockIdx.x, tid = threadIdx.x;

    // inline exclusive scan over g_count -> base_csr for this bucket
    gsc[tid] = (tid < NB) ? g_count[tid] : 0;
    __syncthreads();
    for (int d = 1; d < 256; d <<= 1) {
        int x = (tid >= d) ? gsc[tid - d] : 0;
        __syncthreads();
        gsc[tid] += x;
        __syncthreads();
    }
    const int base_csr = (b > 0) ? gsc[b - 1] : 0;

    int m = g_count[b]; if (m > BCAP) m = BCAP;
    hist[tid] = 0; cnt2[tid] = 0;
    __syncthreads();
    const int* bm = bucket_mem + (size_t)b * BCAP;
    for (int i = tid; i < m; i += 256) {
        int p = bm[i];
        sh_edges[i] = p;
        atomicAdd(&hist[(p >> 16) & 255], 1);
    }
    __syncthreads();
    offs[tid] = hist[tid]; __syncthreads();
    for (int d = 1; d < 256; d <<= 1) {
        int x = (tid >= d) ? offs[tid - d] : 0;
        __syncthreads();
        offs[tid] += x;
        __syncthreads();
    }
    excl[tid] = offs[tid] - hist[tid];
    const int node0 = b << 8;
    if (node0 + tid < N_NODES) row_ptr[node0 + tid] = base_csr + excl[tid];
    if (b == 0 && tid == 0) row_ptr[N_NODES] = ET;
    __syncthreads();
    for (int i = tid; i < m; i += 256) {
        int p = sh_edges[i];
        int dl = (p >> 16) & 255;
        int r = atomicAdd(&cnt2[dl], 1);
        csr_src[base_csr + excl[dl] + r] = (unsigned short)(p & 0xFFFF);
    }
}

// ---------------------------------------------------------------------------
// Fused scores + softmax + aggregate: one wave per dst node, 8 edges per
// unrolled iteration (2 per quarter-wave lane, both row-loads issued first).
// Quarter-wave (16 lanes) per edge; lane covers 8 channels; head = ql/4.
// ---------------------------------------------------------------------------
__global__ __launch_bounds__(256) void fused_agg(
    const float* __restrict__ xl, const float* __restrict__ xr,
    const int* __restrict__ row_ptr, const unsigned short* __restrict__ csr_src,
    const float* __restrict__ att, const float* __restrict__ bias,
    float* __restrict__ out)
{
    int t = threadIdx.x;
    int wave = t >> 6, l = t & 63;
    int q = l >> 4, ql = l & 15;            // quarter-wave id, lane within
    int n = blockIdx.x * 4 + wave;
    if (n >= N_NODES) return;
    int beg = row_ptr[n], end = row_ptr[n + 1];

    const int c0 = 8 * ql;
    const float* xrp = xr + (size_t)n * DF + c0;
    float4 xr0 = *(const float4*)(xrp);
    float4 xr1 = *(const float4*)(xrp + 4);
    float4 at0 = *(const float4*)(att + c0);
    float4 at1 = *(const float4*)(att + c0 + 4);

    float a0 = 0.f, a1 = 0.f, a2 = 0.f, a3 = 0.f;
    float a4 = 0.f, a5 = 0.f, a6 = 0.f, a7 = 0.f, den = 0.f;

    for (int base = beg; base < end; base += 64) {
        int cnt = end - base; if (cnt > 64) cnt = 64;
        int my_src = 0;
        if (base + l < end) my_src = csr_src[base + l];   // coalesced batch load
        int nq = (cnt + 3) >> 2;
        for (int j = 0; j < nq; j += 2) {
            int e0i = 4 * j + q;
            int e1i = e0i + 4;
            int s0 = __shfl(my_src, e0i);
            int s1 = __shfl(my_src, (e1i < 64) ? e1i : 0);
            const float* r0 = xl + (size_t)s0 * DF + c0;
            const float* r1 = xl + (size_t)s1 * DF + c0;
            float4 v0 = *(const float4*)(r0);
            float4 v1 = *(const float4*)(r0 + 4);
            float4 w0, w1;
            bool have2 = (j + 1 < nq);
            if (have2) { w0 = *(const float4*)(r1); w1 = *(const float4*)(r1 + 4); }

            {
                float m0 = v0.x + xr0.x, m1 = v0.y + xr0.y;
                float m2 = v0.z + xr0.z, m3 = v0.w + xr0.w;
                float m4 = v1.x + xr1.x, m5 = v1.y + xr1.y;
                float m6 = v1.z + xr1.z, m7 = v1.w + xr1.w;
                m0 = m0 > 0.f ? m0 : SLOPE * m0;  m1 = m1 > 0.f ? m1 : SLOPE * m1;
                m2 = m2 > 0.f ? m2 : SLOPE * m2;  m3 = m3 > 0.f ? m3 : SLOPE * m3;
                m4 = m4 > 0.f ? m4 : SLOPE * m4;  m5 = m5 > 0.f ? m5 : SLOPE * m5;
                m6 = m6 > 0.f ? m6 : SLOPE * m6;  m7 = m7 > 0.f ? m7 : SLOPE * m7;
                float p = m0 * at0.x + m1 * at0.y + m2 * at0.z + m3 * at0.w
                        + m4 * at1.x + m5 * at1.y + m6 * at1.z + m7 * at1.w;
                p += __shfl_xor(p, 1);
                p += __shfl_xor(p, 2);
                float e = (e0i < cnt) ? __expf(p) : 0.f;
                a0 += e * v0.x; a1 += e * v0.y; a2 += e * v0.z; a3 += e * v0.w;
                a4 += e * v1.x; a5 += e * v1.y; a6 += e * v1.z; a7 += e * v1.w;
                den += e;
            }
            if (have2) {
                float m0 = w0.x + xr0.x, m1 = w0.y + xr0.y;
                float m2 = w0.z + xr0.z, m3 = w0.w + xr0.w;
                float m4 = w1.x + xr1.x, m5 = w1.y + xr1.y;
                float m6 = w1.z + xr1.z, m7 = w1.w + xr1.w;
                m0 = m0 > 0.f ? m0 : SLOPE * m0;  m1 = m1 > 0.f ? m1 : SLOPE * m1;
                m2 = m2 > 0.f ? m2 : SLOPE * m2;  m3 = m3 > 0.f ? m3 : SLOPE * m3;
                m4 = m4 > 0.f ? m4 : SLOPE * m4;  m5 = m5 > 0.f ? m5 : SLOPE * m5;
                m6 = m6 > 0.f ? m6 : SLOPE * m6;  m7 = m7 > 0.f ? m7 : SLOPE * m7;
                float p = m0 * at0.x + m1 * at0.y + m2 * at0.z + m3 * at0.w
                        + m4 * at1.x + m5 * at1.y + m6 * at1.z + m7 * at1.w;
                p += __shfl_xor(p, 1);
                p += __shfl_xor(p, 2);
                float e = (e1i < cnt) ? __expf(p) : 0.f;
                a0 += e * w0.x; a1 += e * w0.y; a2 += e * w0.z; a3 += e * w0.w;
                a4 += e * w1.x; a5 += e * w1.y; a6 += e * w1.z; a7 += e * w1.w;
                den += e;
            }
        }
    }

    // combine the four quarter-wave accumulators (same channels, diff edges)
#define CMB(x) x += __shfl_xor(x, 16); x += __shfl_xor(x, 32);
    CMB(a0) CMB(a1) CMB(a2) CMB(a3) CMB(a4) CMB(a5) CMB(a6) CMB(a7) CMB(den)
#undef CMB

    if (q == 0) {
        float inv = 1.f / (den + 1e-16f);
        float4 b0 = *(const float4*)(bias + c0);
        float4 b1 = *(const float4*)(bias + c0 + 4);
        float4 o0, o1;
        o0.x = fmaxf(a0 * inv + b0.x, 0.f);
        o0.y = fmaxf(a1 * inv + b0.y, 0.f);
        o0.z = fmaxf(a2 * inv + b0.z, 0.f);
        o0.w = fmaxf(a3 * inv + b0.w, 0.f);
        o1.x = fmaxf(a4 * inv + b1.x, 0.f);
        o1.y = fmaxf(a5 * inv + b1.y, 0.f);
        o1.z = fmaxf(a6 * inv + b1.z, 0.f);
        o1.w = fmaxf(a7 * inv + b1.w, 0.f);
        float* op = out + (size_t)n * DF + c0;
        *(float4*)(op)     = o0;
        *(float4*)(op + 4) = o1;
    }
}

// ---------------------------------------------------------------------------
extern "C" void kernel_launch(void* const* d_in, const int* in_sizes, int n_in,
                              void* d_out, int out_size, void* d_ws, size_t ws_size,
                              hipStream_t stream)
{
    (void)in_sizes; (void)n_in; (void)out_size; (void)ws_size;

    const float* x    = (const float*)d_in[0];
    const int*   ei   = (const int*)d_in[1];
    const float* W1l  = (const float*)d_in[2];
    const float* W1r  = (const float*)d_in[3];
    const float* att1 = (const float*)d_in[4];
    const float* b1   = (const float*)d_in[5];
    const float* W2l  = (const float*)d_in[6];
    const float* W2r  = (const float*)d_in[7];
    const float* att2 = (const float*)d_in[8];
    const float* b2   = (const float*)d_in[9];
    float* out = (float*)d_out;

    char* ws = (char*)d_ws;
    size_t off = 0;
    const size_t NF = (size_t)N_NODES * DF * sizeof(float);   // 25.6 MB
    float* A  = (float*)(ws + off); off += NF;                // xl
    float* B  = (float*)(ws + off); off += NF;                // xr
    float* C  = (float*)(ws + off); off += NF;                // layer-1 output h
    int* bucket_mem  = (int*)(ws + off); off += (size_t)NB * BCAP * sizeof(int);
    int* g_count     = (int*)(ws + off); off += 256 * sizeof(int);
    int* row_ptr     = (int*)(ws + off); off += (size_t)(N_NODES + 1) * sizeof(int);
    unsigned short* csr_src = (unsigned short*)(ws + off);
    off += ((size_t)ET * sizeof(unsigned short) + 3) & ~(size_t)3;

    // ---- CSR over dst (shared by both layers) ----
    hipMemsetAsync(g_count, 0, NB * sizeof(int), stream);
    bin_pass<<<(ET + P1_CHUNK - 1) / P1_CHUNK, 256, 0, stream>>>(ei, g_count, bucket_mem);
    csr_pass<<<NB, 256, 0, stream>>>(g_count, bucket_mem, row_ptr, csr_src);

    dim3 gg((N_NODES + 127) / 128, 2);

    // ---- layer 1 ----
    gemm_dual<<<gg, 256, 0, stream>>>(x, W1l, W1r, A, B, N_NODES);
    fused_agg<<<(N_NODES + 3) / 4, 256, 0, stream>>>(A, B, row_ptr, csr_src, att1, b1, C);

    // ---- layer 2 ----
    gemm_dual<<<gg, 256, 0, stream>>>(C, W2l, W2r, A, B, N_NODES);
    fused_agg<<<(N_NODES + 3) / 4, 256, 0, stream>>>(A, B, row_ptr, csr_src, att2, b2, out);
}